// Round 7
// baseline (112.087 us; speedup 1.0000x reference)
//
#include <hip/hip_runtime.h>
#include <math.h>

// PHOSA interaction loss, MI355X — round 7: single-pass LDS-staged design.
// Round-6 counters (hbm 20%, VALU 12%, occ 75%) showed latency-bound random
// gathers. Fix: bucket part indices per 2048-vertex chunk ONCE (deterministic
// stable compaction, batch-independent), then one streaming pass stages each
// chunk in LDS and serves both the batch sums and the part stats from LDS.
// Zero random global reads; HBM traffic = one clean read of both tensors.
constexpr int B_   = 256;
constexpr int NS_  = 10475;
constexpr int NO_  = 65536;
constexpr int P_   = 8;
constexpr int KS_  = 1024;
constexpr int KO_  = 2048;
constexpr float EPS_ = 1e-9f;
constexpr float ZTH_ = 5.0f;

constexpr int CO_   = 2048;               // obj chunk verts
constexpr int NCO_  = NO_ / CO_;          // 32 chunks
constexpr int CS_   = 1310;               // smpl chunk verts (8*1310 >= 10475)
constexpr int NCS_  = 8;
constexpr int CAPO_ = 256;                // bucket capacity (mean 64, 24 sd)
constexpr int CAPS_ = 512;                // bucket capacity (mean 128, 36 sd)
constexpr int VPTO_ = CO_ / 256;          // 8 verts/thread
constexpr int VPTS_ = (CS_ + 255) / 256;  // 6 verts/thread (guarded)

#define DEV_INLINE __device__ __forceinline__

DEV_INLINE float wredsum(float v) {
#pragma unroll
    for (int o = 32; o; o >>= 1) v += __shfl_down(v, o);
    return v;
}
DEV_INLINE float wredmin(float v) {
#pragma unroll
    for (int o = 32; o; o >>= 1) v = fminf(v, __shfl_down(v, o));
    return v;
}
DEV_INLINE float wredmax(float v) {
#pragma unroll
    for (int o = 32; o; o >>= 1) v = fmaxf(v, __shfl_down(v, o));
    return v;
}

// ---------------------------------------------------------------------------
// Kernel 1: deterministic bucket build. One block per (tensor, chunk, part):
// stable stream-compaction of the part's index list into the chunk's bucket.
// Entry = local vertex index; duplicates kept (reference gather semantics).
// ---------------------------------------------------------------------------
__global__ __launch_bounds__(256) void bucket_build_kernel(
        const int* __restrict__ sidx, const int* __restrict__ oidx,
        int* __restrict__ objCnt, int* __restrict__ objBkt,
        int* __restrict__ smplCnt, int* __restrict__ smplBkt) {
    const int t = threadIdx.x;
    __shared__ int scan[256];
    __shared__ int sbase, stot;
    int K; const int* list; int c0, c1; int* bkt; int* cntp;
    if (blockIdx.x < NCO_ * P_) {
        const int c = blockIdx.x % NCO_;
        const int p = blockIdx.x / NCO_;
        K = KO_; list = oidx + (size_t)p * KO_;
        c0 = c * CO_; c1 = c0 + CO_;
        bkt = objBkt + (size_t)(c * P_ + p) * CAPO_;
        cntp = objCnt + (c * P_ + p);
    } else {
        const int u = blockIdx.x - NCO_ * P_;
        const int c = u % NCS_;
        const int p = u / NCS_;
        K = KS_; list = sidx + (size_t)p * KS_;
        c0 = c * CS_; c1 = min(c0 + CS_, NS_);
        bkt = smplBkt + (size_t)(c * P_ + p) * CAPS_;
        cntp = smplCnt + (c * P_ + p);
    }
    if (t == 0) sbase = 0;
    __syncthreads();
    for (int seg = 0; seg < K; seg += 256) {
        const int k = seg + t;
        const int v = (k < K) ? list[k] : -1;
        const int flag = (v >= c0 && v < c1) ? 1 : 0;
        scan[t] = flag;
        __syncthreads();
#pragma unroll
        for (int off = 1; off < 256; off <<= 1) {
            const int x = (t >= off) ? scan[t - off] : 0;
            __syncthreads();
            scan[t] += x;
            __syncthreads();
        }
        if (flag) bkt[sbase + scan[t] - 1] = v - c0;
        if (t == 255) stot = scan[255];
        __syncthreads();
        if (t == 0) sbase += stot;
        __syncthreads();
    }
    if (t == 0) *cntp = sbase;
}

// ---------------------------------------------------------------------------
// Phase-1 chunk body: stream chunk -> batch-sum partial + LDS stage, then
// per-part stats from LDS via the chunk's buckets. Wave w handles parts
// {w, w+4} (9 accumulators at a time, no spill).
// ---------------------------------------------------------------------------
template <int N, int CHUNK, int NCH, int CAP, int VPT>
DEV_INLINE void chunk_body(const float* __restrict__ v,
                           const float* __restrict__ Ks,
                           const int* __restrict__ cnt,
                           const int* __restrict__ bkt,
                           const int b, const int c,
                           float* __restrict__ sums,
                           float* __restrict__ part,
                           float* lds, float (*red)[4]) {
    const int t = threadIdx.x;
    const int c0 = c * CHUNK;
    const int cn = min(CHUNK, N - c0);
    const float* base = v + ((size_t)b * N + (size_t)c0) * 3;
    float sx = 0.f, sy = 0.f, sz = 0.f;
#pragma unroll
    for (int j = 0; j < VPT; ++j) {
        const int i = j * 256 + t;
        if (i < cn) {
            const float* p = base + (size_t)i * 3;
            const float x = p[0], y = p[1], z = p[2];
            sx += x; sy += y; sz += z;
            lds[i * 3 + 0] = x; lds[i * 3 + 1] = y; lds[i * 3 + 2] = z;
        }
    }
    const int lane = t & 63, wv = t >> 6;
    const float r0 = wredsum(sx), r1 = wredsum(sy), r2 = wredsum(sz);
    if (lane == 0) { red[0][wv] = r0; red[1][wv] = r1; red[2][wv] = r2; }
    __syncthreads();   // covers both red[] and the LDS vertex stage
    if (t == 0) {
        float* o = sums + ((size_t)b * NCH + c) * 3;
        o[0] = red[0][0] + red[0][1] + red[0][2] + red[0][3];
        o[1] = red[1][0] + red[1][1] + red[1][2] + red[1][3];
        o[2] = red[2][0] + red[2][1] + red[2][2] + red[2][3];
    }
    const float fx = Ks[b * 9 + 0];
    const float cx = Ks[b * 9 + 2];
    const float fy = Ks[b * 9 + 4];
    const float cy = Ks[b * 9 + 5];
#pragma unroll
    for (int pi = 0; pi < 2; ++pi) {
        const int pp = wv + pi * 4;
        const int bc = cnt[c * P_ + pp];
        const int* bl = bkt + (size_t)(c * P_ + pp) * CAP;
        float umin = INFINITY, umax = -INFINITY;
        float wmin = INFINITY, wmax = -INFINITY;
        float zmn = INFINITY, zmx = -INFINITY;
        float psx = 0.f, psy = 0.f, psz = 0.f;
        for (int e = lane; e < bc; e += 64) {
            const int li = bl[e];
            const float x = lds[li * 3 + 0];
            const float y = lds[li * 3 + 1];
            const float z = lds[li * 3 + 2];
            psx += x; psy += y; psz += z;
            zmn = fminf(zmn, z); zmx = fmaxf(zmx, z);
            float u, w;
            {
#pragma clang fp contract(off)
                const float zd = z + EPS_;
                const float x_ = x / zd;
                const float y_ = (-y) / zd;
                u = fx * x_ + cx;
                w = 1.0f - (fy * y_ + cy);
                u = 2.0f * (u - 0.5f);
                w = 2.0f * (w - 0.5f);
            }
            umin = fminf(umin, u); umax = fmaxf(umax, u);
            wmin = fminf(wmin, w); wmax = fmaxf(wmax, w);
        }
        float r[9];
        r[0] = wredmin(umin); r[1] = wredmax(umax);
        r[2] = wredmin(wmin); r[3] = wredmax(wmax);
        r[4] = wredmin(zmn);  r[5] = wredmax(zmx);
        r[6] = wredsum(psx);  r[7] = wredsum(psy); r[8] = wredsum(psz);
        if (lane == 0) {
            float* o = part + (((size_t)b * NCH + c) * P_ + pp) * 9;
#pragma unroll
            for (int q = 0; q < 9; ++q) o[q] = r[q];
        }
    }
}

__global__ __launch_bounds__(256) void phase1_kernel(
        const float* __restrict__ obj, const float* __restrict__ smpl,
        const float* __restrict__ Ks,
        const int* __restrict__ objCnt, const int* __restrict__ objBkt,
        const int* __restrict__ smplCnt, const int* __restrict__ smplBkt,
        float* __restrict__ sumO, float* __restrict__ sumS,
        float* __restrict__ partO, float* __restrict__ partS) {
    __shared__ float lds[CO_ * 3];   // 24 KB -> 6 blocks/CU
    __shared__ float red[3][4];
    const int gid = blockIdx.x;
    if (gid < B_ * NCO_) {
        const int b = gid / NCO_, c = gid % NCO_;
        chunk_body<NO_, CO_, NCO_, CAPO_, VPTO_>(obj, Ks, objCnt, objBkt, b, c,
                                                 sumO, partO, lds, red);
    } else {
        const int u = gid - B_ * NCO_;
        const int b = u / NCS_, c = u % NCS_;
        chunk_body<NS_, CS_, NCS_, CAPS_, VPTS_>(smpl, Ks, smplCnt, smplBkt, b, c,
                                                 sumS, partS, lds, red);
    }
}

// ---------------------------------------------------------------------------
// Kernel 3: per-batch finish — fold chunk partials into 8x9 stats, then the
// 8x8 pair mask/mse (verbatim round-2 logic). One block (64 thr) per batch.
// ---------------------------------------------------------------------------
__global__ __launch_bounds__(64) void finish_kernel(
        const float* __restrict__ partS, const float* __restrict__ partO,
        float* __restrict__ pairPartial) {
#pragma clang fp contract(off)
    const int b = blockIdx.x;
    const int t = threadIdx.x;
    __shared__ float sS[P_][9];
    __shared__ float sO[P_][9];
    for (int q = t; q < 72; q += 64) {
        const int s = q / 8, p = q % 8;
        const bool isMin = (s == 0 || s == 2 || s == 4);
        const bool isMax = (s == 1 || s == 3 || s == 5);
        {
            const float* po = partO + (size_t)b * NCO_ * 72 + p * 9 + s;
            float acc = isMin ? INFINITY : (isMax ? -INFINITY : 0.f);
            for (int k = 0; k < NCO_; ++k) {
                const float vv = po[(size_t)k * 72];
                acc = isMin ? fminf(acc, vv) : (isMax ? fmaxf(acc, vv) : acc + vv);
            }
            sO[p][s] = acc;
        }
        {
            const float* ps = partS + (size_t)b * NCS_ * 72 + p * 9 + s;
            float acc = isMin ? INFINITY : (isMax ? -INFINITY : 0.f);
            for (int k = 0; k < NCS_; ++k) {
                const float vv = ps[(size_t)k * 72];
                acc = isMin ? fminf(acc, vv) : (isMax ? fmaxf(acc, vv) : acc + vv);
            }
            sS[p][s] = acc;
        }
    }
    __syncthreads();

    const int ps = t >> 3;
    const int po = t & 7;

    const float* ssp = sS[po];
    const float* sop = sO[po];
    const float pcu = (ssp[0] + ssp[1]) * 0.5f;
    const float phu = (ssp[1] - ssp[0]) * 0.5f * 1.5f;
    const float pcw = (ssp[2] + ssp[3]) * 0.5f;
    const float phw = (ssp[3] - ssp[2]) * 0.5f * 1.5f;
    const float px0 = pcu - phu, px1 = pcu + phu;
    const float py0 = pcw - phw, py1 = pcw + phw;
    const float ocu = (sop[0] + sop[1]) * 0.5f;
    const float ohu = (sop[1] - sop[0]) * 0.5f * 1.5f;
    const float ocw = (sop[2] + sop[3]) * 0.5f;
    const float ohw = (sop[3] - sop[2]) * 0.5f * 1.5f;
    const float ox0 = ocu - ohu, ox1 = ocu + ohu;
    const float oy0 = ocw - ohw, oy1 = ocw + ohw;
    const bool ov = !((ox0 > px1) || (px0 > ox1) || (oy0 > py1) || (py0 > oy1));

    const float a  = sS[ps][4];
    const float bm = sS[ps][5];
    const float c  = sO[po][4];
    const float d  = sO[po][5];
    const float gap = fminf(fabsf(c - bm), fabsf(a - d));
    const float zd = ((d >= a) && (bm >= c)) ? 0.f : gap;
    const bool m = ov && (zd < ZTH_);

    const float ms0 = sS[ps][6] / (float)KS_;
    const float ms1 = sS[ps][7] / (float)KS_;
    const float ms2 = sS[ps][8] / (float)KS_;
    const float mo0 = sO[po][6] / (float)KO_;
    const float mo1 = sO[po][7] / (float)KO_;
    const float mo2 = sO[po][8] / (float)KO_;
    const float d0 = ms0 - mo0, d1 = ms1 - mo1, d2 = ms2 - mo2;
    const float pm = (d0 * d0 + d1 * d1 + d2 * d2) / 3.0f;

    float psum = m ? pm : 0.f;
    float pcnt = m ? 1.f : 0.f;
    psum = wredsum(psum);
    pcnt = wredsum(pcnt);
    if (t == 0) {
        pairPartial[(size_t)b * 2 + 0] = psum;
        pairPartial[(size_t)b * 2 + 1] = pcnt;
    }
}

// ---------------------------------------------------------------------------
// Kernel 4: loss_inter + final reduce.
// ---------------------------------------------------------------------------
__global__ __launch_bounds__(256) void last_kernel(
        const float* __restrict__ sumS, const float* __restrict__ sumO,
        const float* __restrict__ pairPartial, float* __restrict__ out) {
    const int t = threadIdx.x;
    float d2 = 0.f;
#pragma unroll
    for (int c = 0; c < 3; ++c) {
        float ss = 0.f, so = 0.f;
#pragma unroll
        for (int k = 0; k < NCS_; ++k) ss += sumS[((size_t)t * NCS_ + k) * 3 + c];
#pragma unroll
        for (int k = 0; k < NCO_; ++k) so += sumO[((size_t)t * NCO_ + k) * 3 + c];
        const float ms = ss / (float)NS_;
        const float mo = so / (float)NO_;
        const float d = ms - mo;
        d2 += d * d;
    }
    float s = pairPartial[(size_t)t * 2 + 0];
    float c2 = pairPartial[(size_t)t * 2 + 1];
    __shared__ float rli[4], rs[4], rc[4];
    const float rl = wredsum(d2);
    const float ss2 = wredsum(s);
    const float cc = wredsum(c2);
    const int lane = t & 63, wv = t >> 6;
    if (lane == 0) { rli[wv] = rl; rs[wv] = ss2; rc[wv] = cc; }
    __syncthreads();
    if (t == 0) {
        const float tot = rli[0] + rli[1] + rli[2] + rli[3];
        out[0] = tot / (3.0f * (float)B_) / (float)B_;
        const float S = rs[0] + rs[1] + rs[2] + rs[3];
        const float C = rc[0] + rc[1] + rc[2] + rc[3];
        out[1] = (C > 0.f) ? (S / C) : 0.f;
    }
}

// ---------------------------------------------------------------------------
extern "C" void kernel_launch(void* const* d_in, const int* in_sizes, int n_in,
                              void* d_out, int out_size, void* d_ws, size_t ws_size,
                              hipStream_t stream) {
    const float* smpl = (const float*)d_in[0];
    const float* obj  = (const float*)d_in[1];
    const float* Ks   = (const float*)d_in[2];
    const int*   sidx = (const int*)d_in[3];
    const int*   oidx = (const int*)d_in[4];
    float* out = (float*)d_out;

    // workspace layout (~3.5 MB)
    int* objCnt  = (int*)d_ws;                               // 256
    int* smplCnt = objCnt + 256;                             // 64 (+pad to 512)
    int* objBkt  = objCnt + 512;                             // 32*8*256 = 65536
    int* smplBkt = objBkt + NCO_ * P_ * CAPO_;               // 8*8*512  = 32768
    float* sumO  = (float*)(smplBkt + NCS_ * P_ * CAPS_);    // 256*32*3 = 24576
    float* sumS  = sumO + (size_t)B_ * NCO_ * 3;             // 256*8*3  = 6144
    float* partO = sumS + (size_t)B_ * NCS_ * 3;             // 256*32*72 = 589824
    float* partS = partO + (size_t)B_ * NCO_ * 72;           // 256*8*72  = 147456
    float* pairP = partS + (size_t)B_ * NCS_ * 72;           // 512

    bucket_build_kernel<<<NCO_ * P_ + NCS_ * P_, 256, 0, stream>>>(
        sidx, oidx, objCnt, objBkt, smplCnt, smplBkt);
    phase1_kernel<<<B_ * NCO_ + B_ * NCS_, 256, 0, stream>>>(
        obj, smpl, Ks, objCnt, objBkt, smplCnt, smplBkt,
        sumO, sumS, partO, partS);
    finish_kernel<<<B_, 64, 0, stream>>>(partS, partO, pairP);
    last_kernel<<<1, 256, 0, stream>>>(sumS, sumO, pairP, out);
}

// Round 8
// 68.789 us; speedup vs baseline: 1.6294x; 1.6294x over previous
//
#include <hip/hip_runtime.h>
#include <math.h>

// PHOSA interaction loss, MI355X — round 8: round-6 fused kernel (proven
// 69.9 us, absmax 0.0) + two scheduling/MLP fixes:
//  (1) gather units of batch-slot s work on slot s-1's batch (same XCD):
//      the previous slot's stream blocks have already pulled that batch's
//      vertex window into the per-XCD L2, so the random gathers L2-hit
//      (~200 cy) instead of HBM-missing (~900 cy).
//  (2) gather loads are issued as an unrolled load phase (8 independent
//      dwordx3 in flight) before the accumulate phase.
// Accumulation orders are bitwise-identical to round 6.
constexpr int B_   = 256;
constexpr int NS_  = 10475;
constexpr int NO_  = 65536;
constexpr int P_   = 8;
constexpr int KS_  = 1024;
constexpr int KO_  = 2048;
constexpr int NBLK_S = 4;    // stream blocks per batch, smpl
constexpr int NBLK_O = 16;   // stream blocks per batch, object
constexpr float EPS_ = 1e-9f;
constexpr float ZTH_ = 5.0f;

// per-batch work units: 16 objsum + 8 objgather + 4 smplsum + 8 smplgather
constexpr int UNITS_PER_B = NBLK_O + P_ + NBLK_S + P_;   // 36
constexpr int NXCD = 8;
constexpr int NSLOT = B_ / NXCD;                         // 32

#define DEV_INLINE __device__ __forceinline__

DEV_INLINE float wredsum(float v) {
#pragma unroll
    for (int o = 32; o; o >>= 1) v += __shfl_down(v, o);
    return v;
}
DEV_INLINE float wredmin(float v) {
#pragma unroll
    for (int o = 32; o; o >>= 1) v = fminf(v, __shfl_down(v, o));
    return v;
}
DEV_INLINE float wredmax(float v) {
#pragma unroll
    for (int o = 32; o; o >>= 1) v = fmaxf(v, __shfl_down(v, o));
    return v;
}

// ---------------------------------------------------------------------------
// Role body: per-batch component partial sums (verbatim round-6).
// ---------------------------------------------------------------------------
template <int N, int NBLK>
DEV_INLINE void batch_sum_body(const float* __restrict__ v, int b, int blk,
                               float* __restrict__ out) {
    const int chunk = (N + NBLK - 1) / NBLK;
    const int s = blk * chunk;
    const int e = min(N, s + chunk);
    const float* base = v + (size_t)b * N * 3;
    float sx = 0.f, sy = 0.f, sz = 0.f;
    for (int i = s + (int)threadIdx.x; i < e; i += 256) {
        const float* p = base + (size_t)i * 3;
        sx += p[0];
        sy += p[1];
        sz += p[2];
    }
    __shared__ float red[3][4];
    float r0 = wredsum(sx), r1 = wredsum(sy), r2 = wredsum(sz);
    const int lane = threadIdx.x & 63, wv = threadIdx.x >> 6;
    if (lane == 0) { red[0][wv] = r0; red[1][wv] = r1; red[2][wv] = r2; }
    __syncthreads();
    if (threadIdx.x == 0) {
        float* o = out + ((size_t)b * NBLK + blk) * 3;
        o[0] = red[0][0] + red[0][1] + red[0][2] + red[0][3];
        o[1] = red[1][0] + red[1][1] + red[1][2] + red[1][3];
        o[2] = red[2][0] + red[2][1] + red[2][2] + red[2][3];
    }
}

// ---------------------------------------------------------------------------
// Role body: per-(batch,part) gather statistics. Same math/order as round 6;
// loads split into an unrolled load phase for memory-level parallelism.
// ---------------------------------------------------------------------------
template <int N, int K>
DEV_INLINE void part_stats_body(const float* __restrict__ v,
                                const int* __restrict__ pidx,
                                const float* __restrict__ Ks, int b, int p,
                                float* __restrict__ out) {
    const float fx = Ks[b * 9 + 0];
    const float cx = Ks[b * 9 + 2];
    const float fy = Ks[b * 9 + 4];
    const float cy = Ks[b * 9 + 5];
    const float* base = v + (size_t)b * N * 3;
    const int* idx = pidx + (size_t)p * K;

    constexpr int ITER = K / 256;
    int ids[ITER];
#pragma unroll
    for (int j = 0; j < ITER; ++j) ids[j] = idx[threadIdx.x + j * 256];

    float vx[ITER], vy[ITER], vz[ITER];
#pragma unroll
    for (int j = 0; j < ITER; ++j) {
        const float* vp = base + (size_t)ids[j] * 3;
        vx[j] = vp[0]; vy[j] = vp[1]; vz[j] = vp[2];
    }

    float umin = INFINITY, umax = -INFINITY, wmin = INFINITY, wmax = -INFINITY;
    float zmin = INFINITY, zmax = -INFINITY;
    float sx = 0.f, sy = 0.f, sz = 0.f;
#pragma unroll
    for (int j = 0; j < ITER; ++j) {
        const float x = vx[j], y = vy[j], z = vz[j];
        sx += x; sy += y; sz += z;
        zmin = fminf(zmin, z); zmax = fmaxf(zmax, z);
        float u, w;
        {
#pragma clang fp contract(off)
            const float zd = z + EPS_;
            const float x_ = x / zd;
            const float y_ = (-y) / zd;
            u = fx * x_ + cx;
            w = 1.0f - (fy * y_ + cy);
            u = 2.0f * (u - 0.5f);
            w = 2.0f * (w - 0.5f);
        }
        umin = fminf(umin, u); umax = fmaxf(umax, u);
        wmin = fminf(wmin, w); wmax = fmaxf(wmax, w);
    }

    __shared__ float red[4][9];
    float r[9];
    r[0] = wredmin(umin); r[1] = wredmax(umax);
    r[2] = wredmin(wmin); r[3] = wredmax(wmax);
    r[4] = wredmin(zmin); r[5] = wredmax(zmax);
    r[6] = wredsum(sx);   r[7] = wredsum(sy); r[8] = wredsum(sz);
    const int lane = threadIdx.x & 63, wv = threadIdx.x >> 6;
    if (lane == 0) {
#pragma unroll
        for (int q = 0; q < 9; ++q) red[wv][q] = r[q];
    }
    __syncthreads();
    if (threadIdx.x == 0) {
        float* o = out + ((size_t)b * P_ + p) * 9;
        o[0] = fminf(fminf(red[0][0], red[1][0]), fminf(red[2][0], red[3][0]));
        o[1] = fmaxf(fmaxf(red[0][1], red[1][1]), fmaxf(red[2][1], red[3][1]));
        o[2] = fminf(fminf(red[0][2], red[1][2]), fminf(red[2][2], red[3][2]));
        o[3] = fmaxf(fmaxf(red[0][3], red[1][3]), fmaxf(red[2][3], red[3][3]));
        o[4] = fminf(fminf(red[0][4], red[1][4]), fminf(red[2][4], red[3][4]));
        o[5] = fmaxf(fmaxf(red[0][5], red[1][5]), fmaxf(red[2][5], red[3][5]));
        o[6] = red[0][6] + red[1][6] + red[2][6] + red[3][6];
        o[7] = red[0][7] + red[1][7] + red[2][7] + red[3][7];
        o[8] = red[0][8] + red[1][8] + red[2][8] + red[3][8];
    }
}

// ---------------------------------------------------------------------------
// Phase 1: gid -> xcd = gid&7, unit = gid>>3, slot = unit/36, role = unit%36.
// Stream roles use batch slot*8+xcd; gather roles use the PREVIOUS slot's
// batch ((slot+31)&31)*8+xcd so their window is already L2-resident.
// role: [0,16) objsum | [16,24) objgather | [24,28) smplsum | [28,36) smplgather
// ---------------------------------------------------------------------------
__global__ __launch_bounds__(256) void phase1_kernel(
        const float* __restrict__ obj, const float* __restrict__ smpl,
        const float* __restrict__ Ks,
        const int* __restrict__ sidx, const int* __restrict__ oidx,
        float* __restrict__ sumO, float* __restrict__ sumS,
        float* __restrict__ statsO, float* __restrict__ statsS) {
    const int gid = blockIdx.x;
    const int xcd = gid & (NXCD - 1);
    const int unit = gid >> 3;
    const int slot = unit / UNITS_PER_B;
    const int role = unit % UNITS_PER_B;
    const int bs = slot * NXCD + xcd;                        // stream batch
    const int bg = ((slot + NSLOT - 1) & (NSLOT - 1)) * NXCD + xcd; // gather batch
    if (role < NBLK_O) {
        batch_sum_body<NO_, NBLK_O>(obj, bs, role, sumO);
    } else if (role < NBLK_O + P_) {
        part_stats_body<NO_, KO_>(obj, oidx, Ks, bg, role - NBLK_O, statsO);
    } else if (role < NBLK_O + P_ + NBLK_S) {
        batch_sum_body<NS_, NBLK_S>(smpl, bs, role - (NBLK_O + P_), sumS);
    } else {
        part_stats_body<NS_, KS_>(smpl, sidx, Ks, bg, role - (NBLK_O + P_ + NBLK_S), statsS);
    }
}

// ---------------------------------------------------------------------------
// Kernel D: per-batch pair masking + partial sums (verbatim round-2/6).
// ---------------------------------------------------------------------------
__global__ __launch_bounds__(64) void pair_kernel(
        const float* __restrict__ statsS, const float* __restrict__ statsO,
        float* __restrict__ partial) {
#pragma clang fp contract(off)
    const int b = blockIdx.x;
    __shared__ float sS[P_][9];
    __shared__ float sO[P_][9];
    const int t = threadIdx.x;
    for (int i = t; i < 2 * P_ * 9; i += 64) {
        if (i < P_ * 9) sS[i / 9][i % 9] = statsS[(size_t)b * P_ * 9 + i];
        else {
            const int u = i - P_ * 9;
            sO[u / 9][u % 9] = statsO[(size_t)b * P_ * 9 + u];
        }
    }
    __syncthreads();

    const int ps = t >> 3;
    const int po = t & 7;

    const float* ssp = sS[po];
    const float* sop = sO[po];
    const float pcu = (ssp[0] + ssp[1]) * 0.5f;
    const float phu = (ssp[1] - ssp[0]) * 0.5f * 1.5f;
    const float pcw = (ssp[2] + ssp[3]) * 0.5f;
    const float phw = (ssp[3] - ssp[2]) * 0.5f * 1.5f;
    const float px0 = pcu - phu, px1 = pcu + phu;
    const float py0 = pcw - phw, py1 = pcw + phw;
    const float ocu = (sop[0] + sop[1]) * 0.5f;
    const float ohu = (sop[1] - sop[0]) * 0.5f * 1.5f;
    const float ocw = (sop[2] + sop[3]) * 0.5f;
    const float ohw = (sop[3] - sop[2]) * 0.5f * 1.5f;
    const float ox0 = ocu - ohu, ox1 = ocu + ohu;
    const float oy0 = ocw - ohw, oy1 = ocw + ohw;
    const bool ov = !((ox0 > px1) || (px0 > ox1) || (oy0 > py1) || (py0 > oy1));

    const float a  = sS[ps][4];
    const float bm = sS[ps][5];
    const float c  = sO[po][4];
    const float d  = sO[po][5];
    const float gap = fminf(fabsf(c - bm), fabsf(a - d));
    const float zd = ((d >= a) && (bm >= c)) ? 0.f : gap;
    const bool m = ov && (zd < ZTH_);

    const float ms0 = sS[ps][6] / (float)KS_;
    const float ms1 = sS[ps][7] / (float)KS_;
    const float ms2 = sS[ps][8] / (float)KS_;
    const float mo0 = sO[po][6] / (float)KO_;
    const float mo1 = sO[po][7] / (float)KO_;
    const float mo2 = sO[po][8] / (float)KO_;
    const float d0 = ms0 - mo0, d1 = ms1 - mo1, d2 = ms2 - mo2;
    const float pm = (d0 * d0 + d1 * d1 + d2 * d2) / 3.0f;

    float psum = m ? pm : 0.f;
    float pcnt = m ? 1.f : 0.f;
    psum = wredsum(psum);
    pcnt = wredsum(pcnt);
    if (t == 0) {
        partial[(size_t)b * 2 + 0] = psum;
        partial[(size_t)b * 2 + 1] = pcnt;
    }
}

// ---------------------------------------------------------------------------
// Kernel E: loss_inter + final reduce (verbatim round-6).
// ---------------------------------------------------------------------------
__global__ __launch_bounds__(256) void last_kernel(
        const float* __restrict__ sumS, const float* __restrict__ sumO,
        const float* __restrict__ pairPartial, float* __restrict__ out) {
    const int t = threadIdx.x;
    float d2 = 0.f;
#pragma unroll
    for (int c = 0; c < 3; ++c) {
        float ss = 0.f, so = 0.f;
#pragma unroll
        for (int k = 0; k < NBLK_S; ++k) ss += sumS[((size_t)t * NBLK_S + k) * 3 + c];
#pragma unroll
        for (int k = 0; k < NBLK_O; ++k) so += sumO[((size_t)t * NBLK_O + k) * 3 + c];
        const float ms = ss / (float)NS_;
        const float mo = so / (float)NO_;
        const float d = ms - mo;
        d2 += d * d;
    }
    float s = pairPartial[(size_t)t * 2 + 0];
    float c2 = pairPartial[(size_t)t * 2 + 1];
    __shared__ float rli[4], rs[4], rc[4];
    const float rl = wredsum(d2);
    const float ss2 = wredsum(s);
    const float cc = wredsum(c2);
    const int lane = t & 63, wv = t >> 6;
    if (lane == 0) { rli[wv] = rl; rs[wv] = ss2; rc[wv] = cc; }
    __syncthreads();
    if (t == 0) {
        const float tot = rli[0] + rli[1] + rli[2] + rli[3];
        out[0] = tot / (3.0f * (float)B_) / (float)B_;
        const float S = rs[0] + rs[1] + rs[2] + rs[3];
        const float C = rc[0] + rc[1] + rc[2] + rc[3];
        out[1] = (C > 0.f) ? (S / C) : 0.f;
    }
}

// ---------------------------------------------------------------------------
extern "C" void kernel_launch(void* const* d_in, const int* in_sizes, int n_in,
                              void* d_out, int out_size, void* d_ws, size_t ws_size,
                              hipStream_t stream) {
    const float* smpl = (const float*)d_in[0];
    const float* obj  = (const float*)d_in[1];
    const float* Ks   = (const float*)d_in[2];
    const int*   sidx = (const int*)d_in[3];
    const int*   oidx = (const int*)d_in[4];
    float* out = (float*)d_out;

    float* w = (float*)d_ws;
    float* sumO   = w;                                 // 256*16*3 = 12288
    float* sumS   = sumO + (size_t)B_ * NBLK_O * 3;    // 256*4*3  = 3072
    float* statsS = sumS + (size_t)B_ * NBLK_S * 3;    // 256*8*9  = 18432
    float* statsO = statsS + (size_t)B_ * P_ * 9;      // 256*8*9  = 18432
    float* pairP  = statsO + (size_t)B_ * P_ * 9;      // 512

    phase1_kernel<<<B_ * UNITS_PER_B, 256, 0, stream>>>(
        obj, smpl, Ks, sidx, oidx, sumO, sumS, statsO, statsS);
    pair_kernel<<<B_, 64, 0, stream>>>(statsS, statsO, pairP);
    last_kernel<<<1, 256, 0, stream>>>(sumS, sumO, pairP, out);
}